// Round 3
// baseline (105.348 us; speedup 1.0000x reference)
//
#include <hip/hip_runtime.h>
#include <hip/hip_bf16.h>

#define DD 32
#define M_ROWS 1000
#define EPS 1e-5f

typedef float f32x16 __attribute__((ext_vector_type(16)));
typedef float f32x4  __attribute__((ext_vector_type(4)));
typedef short bf16x8 __attribute__((ext_vector_type(8)));

// ws layout (floats):
//   fprime @0      (32000)
//   fph    @32000  (32000)
//   g      @64000  (32000)
//   Srow   @96000  (1000)
//   consts @97024  (64)   [0:32)=c, [32]=E, [33]=F
//   eperm  @97088  (32)
//   aextT  @97120  (2560 ushorts = 1280 floats)  [32 d][80 k] bf16

// ---------- A1: adapter FFN + center + S + f'*hg ----------
__global__ __launch_bounds__(256) void adapter_fprime_kernel(
    const float* __restrict__ feat,
    const float* __restrict__ aw1, const float* __restrict__ ab1,
    const float* __restrict__ aw2, const float* __restrict__ ab2,
    const float* __restrict__ ag,  const float* __restrict__ abt,
    const float* __restrict__ hg,
    float* __restrict__ fprime, float* __restrict__ fph, float* __restrict__ Srow)
{
    const int m = blockIdx.x * 256 + threadIdx.x;
    if (m >= M_ROWS) return;
    float x[DD], h[DD], y[DD];
    const float4* xp = reinterpret_cast<const float4*>(feat + m * DD);
#pragma unroll
    for (int q = 0; q < DD / 4; ++q) {
        float4 v = xp[q];
        x[4*q+0] = v.x; x[4*q+1] = v.y; x[4*q+2] = v.z; x[4*q+3] = v.w;
    }
#pragma unroll
    for (int k = 0; k < DD; ++k) h[k] = ab1[k];
#pragma unroll
    for (int d = 0; d < DD; ++d)
#pragma unroll
        for (int k = 0; k < DD; ++k)
            h[k] = fmaf(x[d], aw1[d*DD + k], h[k]);
#pragma unroll
    for (int k = 0; k < DD; ++k) h[k] = fmaxf(h[k], 0.0f);
#pragma unroll
    for (int d = 0; d < DD; ++d) y[d] = x[d] + ab2[d];
#pragma unroll
    for (int k = 0; k < DD; ++k)
#pragma unroll
        for (int d = 0; d < DD; ++d)
            y[d] = fmaf(h[k], aw2[k*DD + d], y[d]);
    float mean = 0.f;
#pragma unroll
    for (int d = 0; d < DD; ++d) mean += y[d];
    mean *= (1.0f / DD);
    float var = 0.f;
#pragma unroll
    for (int d = 0; d < DD; ++d) { float t = y[d] - mean; var = fmaf(t, t, var); }
    var *= (1.0f / DD);
    const float s = rsqrtf(var + EPS);
    float f[DD];
#pragma unroll
    for (int d = 0; d < DD; ++d) f[d] = (y[d] - mean) * s * ag[d] + abt[d];
    float fm = 0.f;
#pragma unroll
    for (int d = 0; d < DD; ++d) fm += f[d];
    fm *= (1.0f / DD);
    float S = 0.f;
    float fp[DD];
#pragma unroll
    for (int d = 0; d < DD; ++d) { fp[d] = f[d] - fm; S = fmaf(fp[d], fp[d], S); }
    Srow[m] = S;
    float4* op  = reinterpret_cast<float4*>(fprime + m * DD);
    float4* op2 = reinterpret_cast<float4*>(fph    + m * DD);
#pragma unroll
    for (int q = 0; q < DD / 4; ++q) {
        float4 v; float4 w;
        v.x = fp[4*q+0]; v.y = fp[4*q+1]; v.z = fp[4*q+2]; v.w = fp[4*q+3];
        w.x = v.x * hg[4*q+0]; w.y = v.y * hg[4*q+1];
        w.z = v.z * hg[4*q+2]; w.w = v.w * hg[4*q+3];
        op[q] = v; op2[q] = w;
    }
}

// ---------- A2: g[m][k] = sum_d fph[m][d] * fw1[d][k] ----------
__global__ __launch_bounds__(256) void gmat_kernel(
    const float* __restrict__ fph, const float* __restrict__ fw1,
    float* __restrict__ g)
{
    const int t = blockIdx.x * 256 + threadIdx.x;   // 32000 threads
    const int m = t >> 5;
    const int k = t & 31;
    if (m >= M_ROWS) return;
    float fp[DD];
    const float4* fp4 = reinterpret_cast<const float4*>(fph + m * DD);
#pragma unroll
    for (int q = 0; q < DD / 4; ++q) {
        float4 v = fp4[q];
        fp[4*q+0] = v.x; fp[4*q+1] = v.y; fp[4*q+2] = v.z; fp[4*q+3] = v.w;
    }
    float acc = 0.f;
#pragma unroll
    for (int d = 0; d < DD; ++d) acc = fmaf(fp[d], fw1[d*DD + k], acc);
    g[m*DD + k] = acc;
}

// ---------- prep: consts + eperm + bf16 extended-A matrix ----------
__global__ void prep_consts_kernel(
    const float* __restrict__ fw1, const float* __restrict__ fb1,
    const float* __restrict__ hbt, const float* __restrict__ fw2,
    const float* __restrict__ fb2, const float* __restrict__ hg,
    const float* __restrict__ fg,  const float* __restrict__ fbt,
    const float* __restrict__ ow,  const float* __restrict__ ob,
    float* __restrict__ consts, float* __restrict__ eperm,
    unsigned short* __restrict__ aextT)
{
    const int t = threadIdx.x;
    if (t < DD) {
        float c = fb1[t];
#pragma unroll
        for (int d = 0; d < DD; ++d) c = fmaf(hbt[d], fw1[d*DD + t], c);
        consts[t] = c;
    }
    if (t == 0) {
        float E = 0.f, F = ob[0];
#pragma unroll
        for (int d = 0; d < DD; ++d) { E += fg[d] * ow[d]; F = fmaf(fbt[d], ow[d], F); }
        consts[32] = E; consts[33] = F;
    }
    if (t < 32) {
        const int r = t & 15, h2 = t >> 4;
        const int d = (r & 3) + 8 * (r >> 2) + 4 * h2;
        eperm[t] = fg[d] * ow[d];
    }
    // aextT[d][k], 32 x 80, bf16:
    //   k<32   : fw2[k][d]
    //   32..63 : (k-32==d) ? hg[d] : 0
    //   k==64  : hbt[d]+fb2[d]
    //   else   : 0
    for (int idx = t; idx < 32 * 80; idx += 256) {
        const int d = idx / 80, k = idx % 80;
        float v = 0.f;
        if (k < 32)        v = fw2[k * DD + d];
        else if (k < 64)   v = (k - 32 == d) ? hg[d] : 0.f;
        else if (k == 64)  v = hbt[d] + fb2[d];
        __hip_bfloat16 b = __float2bfloat16(v);
        aextT[idx] = __builtin_bit_cast(unsigned short, b);
    }
}

static __device__ __forceinline__ void load4(float* dst, const float* src) {
    f32x4 v = *reinterpret_cast<const f32x4*>(src);
    dst[0] = v.x; dst[1] = v.y; dst[2] = v.z; dst[3] = v.w;
}

static __device__ __forceinline__ bf16x8 to_bf16x8(const float* v) {
    bf16x8 r;
#pragma unroll
    for (int e = 0; e < 8; ++e) {
        __hip_bfloat16 b = __float2bfloat16(v[e]);
        r[e] = __builtin_bit_cast(short, b);
    }
    return r;
}

// ---------- pair head: MFMA over 32-pair tiles ----------
// wave = one i x 32 j. C (32x32): col(lane&31)=pair, row=(reg&3)+8*(reg>>2)+4*(lane>>5)=d
__global__ __launch_bounds__(256, 2) void pair_head_kernel(
    const float* __restrict__ fprime, const float* __restrict__ g,
    const float* __restrict__ Srow,   const float* __restrict__ ddg,
    const float* __restrict__ consts, const float* __restrict__ eperm,
    const unsigned short* __restrict__ aextT,
    float* __restrict__ out)
{
    const int tid  = threadIdx.x;
    const int wid  = tid >> 6;
    const int lane = tid & 63;
    const int l5   = lane & 31;
    const int h2   = lane >> 5;
    const int i    = blockIdx.y;
    const int jg   = blockIdx.x * 4 + wid;   // 0..7, each covers 128 j

    // A fragments (loop-invariant): lane holds A[d=l5][k = 16*t + h2*8 + e]
    bf16x8 afrag[5];
#pragma unroll
    for (int tt = 0; tt < 5; ++tt)
        afrag[tt] = *reinterpret_cast<const bf16x8*>(aextT + l5 * 80 + tt * 16 + h2 * 8);

    const int kA = h2 * 8, kB = 16 + h2 * 8;
    const float* fi = fprime + i * DD;
    const float* gi = g      + i * DD;
    float gik[16], fik[16], ck[16], ep[16];
    load4(gik + 0,  gi + kA); load4(gik + 4,  gi + kA + 4);
    load4(gik + 8,  gi + kB); load4(gik + 12, gi + kB + 4);
    load4(fik + 0,  fi + kA); load4(fik + 4,  fi + kA + 4);
    load4(fik + 8,  fi + kB); load4(fik + 12, fi + kB + 4);
    load4(ck + 0,  consts + kA); load4(ck + 4,  consts + kA + 4);
    load4(ck + 8,  consts + kB); load4(ck + 12, consts + kB + 4);
    load4(ep + 0,  eperm + h2 * 16);     load4(ep + 4,  eperm + h2 * 16 + 4);
    load4(ep + 8,  eperm + h2 * 16 + 8); load4(ep + 12, eperm + h2 * 16 + 12);
    const float Si = Srow[i];
    const float di = ddg[i];
    const float E = consts[32], F = consts[33];

#pragma unroll 1
    for (int tt = 0; tt < 4; ++tt) {
        const int j  = jg * 128 + tt * 32 + l5;
        const int jc = j < M_ROWS ? j : M_ROWS - 1;
        const float* fjp = fprime + jc * DD;
        float fj[DD];
#pragma unroll
        for (int q = 0; q < DD / 4; ++q) load4(fj + 4 * q, fjp + 4 * q);
        const float Sj = Srow[jc];
        const float dj = ddg[jc];
        float gj[16];
        load4(gj + 0, g + jc * DD + kA); load4(gj + 4,  g + jc * DD + kA + 4);
        load4(gj + 8, g + jc * DD + kB); load4(gj + 12, g + jc * DD + kB + 4);

        float qdot = 0.f;
#pragma unroll
        for (int d = 0; d < DD; ++d) qdot = fmaf(fi[d], fj[d], qdot);
        const float s = rsqrtf(fmaf(2.f * qdot + Si + Sj, 1.0f / DD, EPS));

        // h (k-slices kA..kA+7, kB..kB+7) and s*p slices
        float hv[16], b2[16];
#pragma unroll
        for (int e = 0; e < 16; ++e)
            hv[e] = fmaxf(fmaf(s, gik[e] + gj[e], ck[e]), 0.f);
#pragma unroll
        for (int e = 0; e < 8; ++e) {
            const float fjA = h2 ? fj[8 + e]  : fj[e];
            const float fjB = h2 ? fj[24 + e] : fj[16 + e];
            b2[e]     = s * (fik[e]     + fjA);
            b2[8 + e] = s * (fik[8 + e] + fjB);
        }
        bf16x8 B0 = to_bf16x8(hv);
        bf16x8 B1 = to_bf16x8(hv + 8);
        bf16x8 B2 = to_bf16x8(b2);
        bf16x8 B3 = to_bf16x8(b2 + 8);
        bf16x8 B4 = {};
        B4[0] = h2 ? (short)0 : (short)0x3F80;   // bf16 1.0 at k==64

        f32x16 acc;
#pragma unroll
        for (int r = 0; r < 16; ++r) acc[r] = 0.f;
        acc = __builtin_amdgcn_mfma_f32_32x32x16_bf16(afrag[0], B0, acc, 0, 0, 0);
        acc = __builtin_amdgcn_mfma_f32_32x32x16_bf16(afrag[1], B1, acc, 0, 0, 0);
        acc = __builtin_amdgcn_mfma_f32_32x32x16_bf16(afrag[2], B2, acc, 0, 0, 0);
        acc = __builtin_amdgcn_mfma_f32_32x32x16_bf16(afrag[3], B3, acc, 0, 0, 0);
        acc = __builtin_amdgcn_mfma_f32_32x32x16_bf16(afrag[4], B4, acc, 0, 0, 0);

        // epilogue: LN2 folded into dot(ow); reductions over d (16 in-lane + half swap)
        float sy = 0.f, syy = 0.f, sye = 0.f;
#pragma unroll
        for (int r = 0; r < 16; ++r) {
            const float yv = acc[r];
            sy += yv; syy = fmaf(yv, yv, syy); sye = fmaf(yv, ep[r], sye);
        }
        sy  += __shfl_xor(sy, 32);
        syy += __shfl_xor(syy, 32);
        sye += __shfl_xor(sye, 32);
        const float m2   = sy * (1.0f / DD);
        const float var2 = fmaf(-m2, m2, syy * (1.0f / DD));
        const float s2   = rsqrtf(var2 + EPS);
        const float res  = fmaf(s2, fmaf(-m2, E, sye), F) + di + dj;
        if (h2 == 0 && j < M_ROWS) out[i * M_ROWS + j] = res;
    }
}

extern "C" void kernel_launch(void* const* d_in, const int* in_sizes, int n_in,
                              void* d_out, int out_size, void* d_ws, size_t ws_size,
                              hipStream_t stream) {
    const float* feat = (const float*)d_in[0];
    const float* ddg  = (const float*)d_in[1];
    const float* aw1  = (const float*)d_in[2];
    const float* ab1  = (const float*)d_in[3];
    const float* aw2  = (const float*)d_in[4];
    const float* ab2  = (const float*)d_in[5];
    const float* ag   = (const float*)d_in[6];
    const float* abt  = (const float*)d_in[7];
    const float* hg   = (const float*)d_in[8];
    const float* hbt  = (const float*)d_in[9];
    const float* fw1  = (const float*)d_in[10];
    const float* fb1  = (const float*)d_in[11];
    const float* fw2  = (const float*)d_in[12];
    const float* fb2  = (const float*)d_in[13];
    const float* fg   = (const float*)d_in[14];
    const float* fbt  = (const float*)d_in[15];
    const float* ow   = (const float*)d_in[16];
    const float* ob   = (const float*)d_in[17];
    float* out = (float*)d_out;

    float* ws      = (float*)d_ws;
    float* fprime  = ws;             // 32000
    float* fph     = ws + 32000;     // 32000
    float* g       = ws + 64000;     // 32000
    float* Srow    = ws + 96000;     // 1000
    float* consts  = ws + 97024;     // 64
    float* eperm   = ws + 97088;     // 32
    unsigned short* aextT = (unsigned short*)(ws + 97120);  // 2560 ushorts

    adapter_fprime_kernel<<<dim3((M_ROWS + 255) / 256), dim3(256), 0, stream>>>(
        feat, aw1, ab1, aw2, ab2, ag, abt, hg, fprime, fph, Srow);
    gmat_kernel<<<dim3(125), dim3(256), 0, stream>>>(fph, fw1, g);
    prep_consts_kernel<<<dim3(1), dim3(256), 0, stream>>>(
        fw1, fb1, hbt, fw2, fb2, hg, fg, fbt, ow, ob, consts, eperm, aextT);
    pair_head_kernel<<<dim3(2, M_ROWS), dim3(256), 0, stream>>>(
        fprime, g, Srow, ddg, consts, eperm, aextT, out);
}

// Round 4
// 99.364 us; speedup vs baseline: 1.0602x; 1.0602x over previous
//
#include <hip/hip_runtime.h>
#include <hip/hip_bf16.h>

#define DD 32
#define M_ROWS 1000
#define EPS 1e-5f

typedef float f32x16 __attribute__((ext_vector_type(16)));
typedef float f32x4  __attribute__((ext_vector_type(4)));
typedef short bf16x8 __attribute__((ext_vector_type(8)));

// ws layout (floats):
//   fprime @0      (32000)
//   g      @32000  (32000)
//   Srow   @64000  (1000)
//   consts @65024  (64)   [0:32)=c, [32]=E, [33]=F
//   eperm  @65088  (32)
//   aextT  @65120  (2560 ushorts)  [32 d][80 k] bf16

// ---------- front: adapter FFN + center + S + g-row, plus prep block ----------
__global__ __launch_bounds__(64) void front_kernel(
    const float* __restrict__ feat,
    const float* __restrict__ aw1, const float* __restrict__ ab1,
    const float* __restrict__ aw2, const float* __restrict__ ab2,
    const float* __restrict__ ag,  const float* __restrict__ abt,
    const float* __restrict__ hg,
    const float* __restrict__ fw1, const float* __restrict__ fb1,
    const float* __restrict__ hbt, const float* __restrict__ fw2,
    const float* __restrict__ fb2, const float* __restrict__ fg,
    const float* __restrict__ fbt, const float* __restrict__ ow,
    const float* __restrict__ ob,
    float* __restrict__ fprime, float* __restrict__ g, float* __restrict__ Srow,
    float* __restrict__ consts, float* __restrict__ eperm,
    unsigned short* __restrict__ aextT)
{
    const int t = threadIdx.x;
    if (blockIdx.x == 16) {
        // ---- prep ----
        if (t < DD) {
            float c = fb1[t];
#pragma unroll
            for (int d = 0; d < DD; ++d) c = fmaf(hbt[d], fw1[d*DD + t], c);
            consts[t] = c;
            const int r = t & 15, h2 = t >> 4;
            const int d = (r & 3) + 8 * (r >> 2) + 4 * h2;
            eperm[t] = fg[d] * ow[d];
        }
        if (t == 0) {
            float E = 0.f, F = ob[0];
#pragma unroll
            for (int d = 0; d < DD; ++d) { E += fg[d] * ow[d]; F = fmaf(fbt[d], ow[d], F); }
            consts[32] = E; consts[33] = F;
        }
        // aextT[d][k], 32 x 80, bf16
        for (int idx = t; idx < 32 * 80; idx += 64) {
            const int d = idx / 80, k = idx % 80;
            float v = 0.f;
            if (k < 32)        v = fw2[k * DD + d];
            else if (k < 64)   v = (k - 32 == d) ? hg[d] : 0.f;
            else if (k == 64)  v = hbt[d] + fb2[d];
            __hip_bfloat16 b = __float2bfloat16(v);
            aextT[idx] = __builtin_bit_cast(unsigned short, b);
        }
        return;
    }
    const int m = blockIdx.x * 64 + t;
    if (m >= M_ROWS) return;
    float x[DD], h[DD], y[DD];
    const float4* xp = reinterpret_cast<const float4*>(feat + m * DD);
#pragma unroll
    for (int q = 0; q < DD / 4; ++q) {
        float4 v = xp[q];
        x[4*q+0] = v.x; x[4*q+1] = v.y; x[4*q+2] = v.z; x[4*q+3] = v.w;
    }
#pragma unroll
    for (int k = 0; k < DD; ++k) h[k] = ab1[k];
#pragma unroll
    for (int d = 0; d < DD; ++d)
#pragma unroll
        for (int k = 0; k < DD; ++k)
            h[k] = fmaf(x[d], aw1[d*DD + k], h[k]);
#pragma unroll
    for (int k = 0; k < DD; ++k) h[k] = fmaxf(h[k], 0.0f);
#pragma unroll
    for (int d = 0; d < DD; ++d) y[d] = x[d] + ab2[d];
#pragma unroll
    for (int k = 0; k < DD; ++k)
#pragma unroll
        for (int d = 0; d < DD; ++d)
            y[d] = fmaf(h[k], aw2[k*DD + d], y[d]);
    float mean = 0.f;
#pragma unroll
    for (int d = 0; d < DD; ++d) mean += y[d];
    mean *= (1.0f / DD);
    float var = 0.f;
#pragma unroll
    for (int d = 0; d < DD; ++d) { float tv = y[d] - mean; var = fmaf(tv, tv, var); }
    var *= (1.0f / DD);
    const float s = rsqrtf(var + EPS);
    float f[DD];
#pragma unroll
    for (int d = 0; d < DD; ++d) f[d] = (y[d] - mean) * s * ag[d] + abt[d];
    float fm = 0.f;
#pragma unroll
    for (int d = 0; d < DD; ++d) fm += f[d];
    fm *= (1.0f / DD);
    float S = 0.f;
    float fp[DD];
#pragma unroll
    for (int d = 0; d < DD; ++d) { fp[d] = f[d] - fm; S = fmaf(fp[d], fp[d], S); }
    Srow[m] = S;
    // g row: (fp .* hg) @ fw1
    float fph[DD], gr[DD];
#pragma unroll
    for (int d = 0; d < DD; ++d) fph[d] = fp[d] * hg[d];
#pragma unroll
    for (int k = 0; k < DD; ++k) gr[k] = 0.f;
#pragma unroll
    for (int d = 0; d < DD; ++d)
#pragma unroll
        for (int k = 0; k < DD; ++k)
            gr[k] = fmaf(fph[d], fw1[d*DD + k], gr[k]);
    float4* op  = reinterpret_cast<float4*>(fprime + m * DD);
    float4* og  = reinterpret_cast<float4*>(g      + m * DD);
#pragma unroll
    for (int q = 0; q < DD / 4; ++q) {
        float4 v, w;
        v.x = fp[4*q+0]; v.y = fp[4*q+1]; v.z = fp[4*q+2]; v.w = fp[4*q+3];
        w.x = gr[4*q+0]; w.y = gr[4*q+1]; w.z = gr[4*q+2]; w.w = gr[4*q+3];
        op[q] = v; og[q] = w;
    }
}

static __device__ __forceinline__ void load4(float* dst, const float* src) {
    f32x4 v = *reinterpret_cast<const f32x4*>(src);
    dst[0] = v.x; dst[1] = v.y; dst[2] = v.z; dst[3] = v.w;
}

static __device__ __forceinline__ bf16x8 to_bf16x8(const float* v) {
    bf16x8 r;
#pragma unroll
    for (int e = 0; e < 8; ++e) {
        __hip_bfloat16 b = __float2bfloat16(v[e]);
        r[e] = __builtin_bit_cast(short, b);
    }
    return r;
}

// ---------- pair head: MFMA over 32-pair tiles ----------
// wave = one i x 32 j. C (32x32): col(lane&31)=pair, row=(reg&3)+8*(reg>>2)+4*(lane>>5)=d
__global__ __launch_bounds__(256, 2) void pair_head_kernel(
    const float* __restrict__ fprime, const float* __restrict__ g,
    const float* __restrict__ Srow,   const float* __restrict__ ddg,
    const float* __restrict__ consts, const float* __restrict__ eperm,
    const unsigned short* __restrict__ aextT,
    float* __restrict__ out)
{
    const int tid  = threadIdx.x;
    const int wid  = tid >> 6;
    const int lane = tid & 63;
    const int l5   = lane & 31;
    const int h2   = lane >> 5;
    const int i    = blockIdx.y;
    const int jg   = blockIdx.x * 4 + wid;   // 0..7, each covers 128 j

    // A fragments (loop-invariant): lane holds A[d=l5][k = 16*t + h2*8 + e]
    bf16x8 afrag[5];
#pragma unroll
    for (int tt = 0; tt < 5; ++tt)
        afrag[tt] = *reinterpret_cast<const bf16x8*>(aextT + l5 * 80 + tt * 16 + h2 * 8);

    // i-side: uniform pointers -> scalar loads; h2-dependent slices via ternary
    const float* __restrict__ fi = fprime + i * DD;
    const float* __restrict__ gi = g      + i * DD;
    float fik[16], gik[16], ck[16], ep[16];
#pragma unroll
    for (int e = 0; e < 8; ++e) {
        fik[e]     = h2 ? fi[8 + e]  : fi[e];
        fik[8 + e] = h2 ? fi[24 + e] : fi[16 + e];
        gik[e]     = h2 ? gi[8 + e]  : gi[e];
        gik[8 + e] = h2 ? gi[24 + e] : gi[16 + e];
        ck[e]      = h2 ? consts[8 + e]  : consts[e];
        ck[8 + e]  = h2 ? consts[24 + e] : consts[16 + e];
    }
#pragma unroll
    for (int r = 0; r < 16; ++r) ep[r] = h2 ? eperm[16 + r] : eperm[r];
    const float Si = Srow[i];
    const float di = ddg[i];
    const float E = consts[32], F = consts[33];

#pragma unroll 1
    for (int tt = 0; tt < 4; ++tt) {
        const int j  = jg * 128 + tt * 32 + l5;
        const int jc = j < M_ROWS ? j : M_ROWS - 1;
        const float* fjp = fprime + jc * DD;
        float fj[DD];
#pragma unroll
        for (int q = 0; q < DD / 4; ++q) load4(fj + 4 * q, fjp + 4 * q);
        const float Sj = Srow[jc];
        const float dj = ddg[jc];
        const float* gjp = g + jc * DD + h2 * 8;
        float gj[16];
        load4(gj + 0,  gjp);      load4(gj + 4,  gjp + 4);
        load4(gj + 8,  gjp + 16); load4(gj + 12, gjp + 20);

        float qdot = 0.f;
#pragma unroll
        for (int d = 0; d < DD; ++d) qdot = fmaf(fi[d], fj[d], qdot);
        const float s = rsqrtf(fmaf(2.f * qdot + Si + Sj, 1.0f / DD, EPS));

        // h (k-slices h2*8.., 16+h2*8..) and s*p slices
        float hv[16], b2[16];
#pragma unroll
        for (int e = 0; e < 16; ++e)
            hv[e] = fmaxf(fmaf(s, gik[e] + gj[e], ck[e]), 0.f);
#pragma unroll
        for (int e = 0; e < 8; ++e) {
            const float fjA = h2 ? fj[8 + e]  : fj[e];
            const float fjB = h2 ? fj[24 + e] : fj[16 + e];
            b2[e]     = s * (fik[e]     + fjA);
            b2[8 + e] = s * (fik[8 + e] + fjB);
        }
        bf16x8 B0 = to_bf16x8(hv);
        bf16x8 B1 = to_bf16x8(hv + 8);
        bf16x8 B2 = to_bf16x8(b2);
        bf16x8 B3 = to_bf16x8(b2 + 8);
        bf16x8 B4 = {};
        B4[0] = h2 ? (short)0 : (short)0x3F80;   // bf16 1.0 at k==64

        f32x16 acc;
#pragma unroll
        for (int r = 0; r < 16; ++r) acc[r] = 0.f;
        acc = __builtin_amdgcn_mfma_f32_32x32x16_bf16(afrag[0], B0, acc, 0, 0, 0);
        acc = __builtin_amdgcn_mfma_f32_32x32x16_bf16(afrag[1], B1, acc, 0, 0, 0);
        acc = __builtin_amdgcn_mfma_f32_32x32x16_bf16(afrag[2], B2, acc, 0, 0, 0);
        acc = __builtin_amdgcn_mfma_f32_32x32x16_bf16(afrag[3], B3, acc, 0, 0, 0);
        acc = __builtin_amdgcn_mfma_f32_32x32x16_bf16(afrag[4], B4, acc, 0, 0, 0);

        // epilogue: LN2 folded into dot(ow)
        float sy = 0.f, syy = 0.f, sye = 0.f;
#pragma unroll
        for (int r = 0; r < 16; ++r) {
            const float yv = acc[r];
            sy += yv; syy = fmaf(yv, yv, syy); sye = fmaf(yv, ep[r], sye);
        }
        sy  += __shfl_xor(sy, 32);
        syy += __shfl_xor(syy, 32);
        sye += __shfl_xor(sye, 32);
        const float m2   = sy * (1.0f / DD);
        const float var2 = fmaf(-m2, m2, syy * (1.0f / DD));
        const float s2   = rsqrtf(var2 + EPS);
        const float res  = fmaf(s2, fmaf(-m2, E, sye), F) + di + dj;
        if (h2 == 0 && j < M_ROWS) out[i * M_ROWS + j] = res;
    }
}

extern "C" void kernel_launch(void* const* d_in, const int* in_sizes, int n_in,
                              void* d_out, int out_size, void* d_ws, size_t ws_size,
                              hipStream_t stream) {
    const float* feat = (const float*)d_in[0];
    const float* ddg  = (const float*)d_in[1];
    const float* aw1  = (const float*)d_in[2];
    const float* ab1  = (const float*)d_in[3];
    const float* aw2  = (const float*)d_in[4];
    const float* ab2  = (const float*)d_in[5];
    const float* ag   = (const float*)d_in[6];
    const float* abt  = (const float*)d_in[7];
    const float* hg   = (const float*)d_in[8];
    const float* hbt  = (const float*)d_in[9];
    const float* fw1  = (const float*)d_in[10];
    const float* fb1  = (const float*)d_in[11];
    const float* fw2  = (const float*)d_in[12];
    const float* fb2  = (const float*)d_in[13];
    const float* fg   = (const float*)d_in[14];
    const float* fbt  = (const float*)d_in[15];
    const float* ow   = (const float*)d_in[16];
    const float* ob   = (const float*)d_in[17];
    float* out = (float*)d_out;

    float* ws      = (float*)d_ws;
    float* fprime  = ws;             // 32000
    float* g       = ws + 32000;     // 32000
    float* Srow    = ws + 64000;     // 1000
    float* consts  = ws + 65024;     // 64
    float* eperm   = ws + 65088;     // 32
    unsigned short* aextT = (unsigned short*)(ws + 65120);  // 2560 ushorts

    front_kernel<<<dim3(17), dim3(64), 0, stream>>>(
        feat, aw1, ab1, aw2, ab2, ag, abt, hg,
        fw1, fb1, hbt, fw2, fb2, fg, fbt, ow, ob,
        fprime, g, Srow, consts, eperm, aextT);
    pair_head_kernel<<<dim3(2, M_ROWS), dim3(256), 0, stream>>>(
        fprime, g, Srow, ddg, consts, eperm, aextT, out);
}

// Round 5
// 59.853 us; speedup vs baseline: 1.7601x; 1.6601x over previous
//
#include <hip/hip_runtime.h>
#include <hip/hip_bf16.h>

#define DD 32
#define M_ROWS 1000
#define EPS 1e-5f

typedef float f32x16 __attribute__((ext_vector_type(16)));
typedef float f32x8  __attribute__((ext_vector_type(8)));
typedef float f32x4  __attribute__((ext_vector_type(4)));
typedef short bf16x8 __attribute__((ext_vector_type(8)));

// ws layout (floats):
//   g      @0      (32000)   g[m][k] = (f'_m . hg) @ fw1
//   fphg   @32000  (32000)   f'_m[d]*hg[d]
//   Srow   @64000  (1000)
//   consts @65024  (64)   [0:32)=c, [32]=E, [33]=F
//   eperm  @65088  (32)   fg[d]*ow[d], C-layout permuted
//   cbperm @65120  (32)   hbt[d]+fb2[d], C-layout permuted
//   aextT  @65152  (512 floats = 1024 ushorts)  fw2^T as bf16 [32 d][32 k]
//   fpb    @65664  (16000 floats = 32000 ushorts) f' rows in bf16

static __device__ __forceinline__ bf16x8 to_bf16x8p(const float* v) {
    bf16x8 r;
#pragma unroll
    for (int e = 0; e < 8; ++e) {
        __hip_bfloat16 b = __float2bfloat16(v[e]);
        r[e] = __builtin_bit_cast(short, b);
    }
    return r;
}

static __device__ __forceinline__ bf16x8 cvt8(f32x8 v) {
    bf16x8 r;
#pragma unroll
    for (int e = 0; e < 8; ++e) {
        __hip_bfloat16 b = __float2bfloat16(v[e]);
        r[e] = __builtin_bit_cast(short, b);
    }
    return r;
}

// ---------- front: adapter FFN + center + S + g-row + bf16 copy, plus prep ----------
__global__ __launch_bounds__(64) void front_kernel(
    const float* __restrict__ feat,
    const float* __restrict__ aw1, const float* __restrict__ ab1,
    const float* __restrict__ aw2, const float* __restrict__ ab2,
    const float* __restrict__ ag,  const float* __restrict__ abt,
    const float* __restrict__ hg,
    const float* __restrict__ fw1, const float* __restrict__ fb1,
    const float* __restrict__ hbt, const float* __restrict__ fw2,
    const float* __restrict__ fb2, const float* __restrict__ fg,
    const float* __restrict__ fbt, const float* __restrict__ ow,
    const float* __restrict__ ob,
    float* __restrict__ g, float* __restrict__ fphg, float* __restrict__ Srow,
    float* __restrict__ consts, float* __restrict__ eperm, float* __restrict__ cbperm,
    unsigned short* __restrict__ aextT, unsigned short* __restrict__ fpb)
{
    const int t = threadIdx.x;
    if (blockIdx.x == 16) {
        if (t < DD) {
            float c = fb1[t];
#pragma unroll
            for (int d = 0; d < DD; ++d) c = fmaf(hbt[d], fw1[d*DD + t], c);
            consts[t] = c;
            const int r = t & 15, hh = t >> 4;
            const int d = (r & 3) + 8 * (r >> 2) + 4 * hh;
            eperm[t]  = fg[d] * ow[d];
            cbperm[t] = hbt[d] + fb2[d];
        }
        if (t == 0) {
            float E = 0.f, F = ob[0];
#pragma unroll
            for (int d = 0; d < DD; ++d) { E += fg[d] * ow[d]; F = fmaf(fbt[d], ow[d], F); }
            consts[32] = E; consts[33] = F;
        }
        // aextT[d][k] = fw2[k][d], bf16
        for (int idx = t; idx < 32 * 32; idx += 64) {
            const int d = idx >> 5, k = idx & 31;
            __hip_bfloat16 b = __float2bfloat16(fw2[k * DD + d]);
            aextT[idx] = __builtin_bit_cast(unsigned short, b);
        }
        return;
    }
    const int m = blockIdx.x * 64 + t;
    if (m >= M_ROWS) return;
    float x[DD], h[DD], y[DD];
    const float4* xp = reinterpret_cast<const float4*>(feat + m * DD);
#pragma unroll
    for (int q = 0; q < DD / 4; ++q) {
        float4 v = xp[q];
        x[4*q+0] = v.x; x[4*q+1] = v.y; x[4*q+2] = v.z; x[4*q+3] = v.w;
    }
#pragma unroll
    for (int k = 0; k < DD; ++k) h[k] = ab1[k];
#pragma unroll
    for (int d = 0; d < DD; ++d)
#pragma unroll
        for (int k = 0; k < DD; ++k)
            h[k] = fmaf(x[d], aw1[d*DD + k], h[k]);
#pragma unroll
    for (int k = 0; k < DD; ++k) h[k] = fmaxf(h[k], 0.0f);
#pragma unroll
    for (int d = 0; d < DD; ++d) y[d] = x[d] + ab2[d];
#pragma unroll
    for (int k = 0; k < DD; ++k)
#pragma unroll
        for (int d = 0; d < DD; ++d)
            y[d] = fmaf(h[k], aw2[k*DD + d], y[d]);
    float mean = 0.f;
#pragma unroll
    for (int d = 0; d < DD; ++d) mean += y[d];
    mean *= (1.0f / DD);
    float var = 0.f;
#pragma unroll
    for (int d = 0; d < DD; ++d) { float tv = y[d] - mean; var = fmaf(tv, tv, var); }
    var *= (1.0f / DD);
    const float s = rsqrtf(var + EPS);
    float f[DD];
#pragma unroll
    for (int d = 0; d < DD; ++d) f[d] = (y[d] - mean) * s * ag[d] + abt[d];
    float fm = 0.f;
#pragma unroll
    for (int d = 0; d < DD; ++d) fm += f[d];
    fm *= (1.0f / DD);
    float S = 0.f;
    float fp[DD];
#pragma unroll
    for (int d = 0; d < DD; ++d) { fp[d] = f[d] - fm; S = fmaf(fp[d], fp[d], S); }
    Srow[m] = S;
    // fph = fp .* hg ; g row = fph @ fw1
    float fph[DD], gr[DD];
#pragma unroll
    for (int d = 0; d < DD; ++d) fph[d] = fp[d] * hg[d];
#pragma unroll
    for (int k = 0; k < DD; ++k) gr[k] = 0.f;
#pragma unroll
    for (int d = 0; d < DD; ++d)
#pragma unroll
        for (int k = 0; k < DD; ++k)
            gr[k] = fmaf(fph[d], fw1[d*DD + k], gr[k]);
    float4* og  = reinterpret_cast<float4*>(g    + m * DD);
    float4* oph = reinterpret_cast<float4*>(fphg + m * DD);
#pragma unroll
    for (int q = 0; q < DD / 4; ++q) {
        float4 v, w;
        v.x = gr[4*q+0];  v.y = gr[4*q+1];  v.z = gr[4*q+2];  v.w = gr[4*q+3];
        w.x = fph[4*q+0]; w.y = fph[4*q+1]; w.z = fph[4*q+2]; w.w = fph[4*q+3];
        og[q] = v; oph[q] = w;
    }
    bf16x8* ob16 = reinterpret_cast<bf16x8*>(fpb + m * DD);
#pragma unroll
    for (int q = 0; q < DD / 8; ++q)
        ob16[q] = to_bf16x8p(fp + 8 * q);
}

// ---------- gram: Q = F' F'^T (bf16 MFMA), written into d_out ----------
__global__ __launch_bounds__(256) void gram_kernel(
    const unsigned short* __restrict__ fpb, float* __restrict__ Q)
{
    const int tid = threadIdx.x;
    const int wid = tid >> 6;
    const int l5  = (tid & 63) & 31;
    const int h2  = (tid & 63) >> 5;
    const int ib  = blockIdx.y;
    const int jb  = blockIdx.x * 4 + wid;

    int ri = ib * 32 + l5; if (ri > M_ROWS - 1) ri = M_ROWS - 1;
    int rj = jb * 32 + l5; if (rj > M_ROWS - 1) rj = M_ROWS - 1;
    bf16x8 a0 = *reinterpret_cast<const bf16x8*>(fpb + ri * DD + h2 * 8);
    bf16x8 a1 = *reinterpret_cast<const bf16x8*>(fpb + ri * DD + 16 + h2 * 8);
    bf16x8 b0 = *reinterpret_cast<const bf16x8*>(fpb + rj * DD + h2 * 8);
    bf16x8 b1 = *reinterpret_cast<const bf16x8*>(fpb + rj * DD + 16 + h2 * 8);

    f32x16 acc;
#pragma unroll
    for (int r = 0; r < 16; ++r) acc[r] = 0.f;
    acc = __builtin_amdgcn_mfma_f32_32x32x16_bf16(a0, b0, acc, 0, 0, 0);
    acc = __builtin_amdgcn_mfma_f32_32x32x16_bf16(a1, b1, acc, 0, 0, 0);

#pragma unroll
    for (int r = 0; r < 16; ++r) {
        const int row = (r & 3) + 8 * (r >> 2) + 4 * h2;
        const int gi_ = ib * 32 + row;
        const int gj_ = jb * 32 + l5;
        if (gi_ < M_ROWS && gj_ < M_ROWS)
            Q[gi_ * M_ROWS + gj_] = acc[r];
    }
}

// ---------- pair head: 2 MFMAs per 32-pair tile, array-free ----------
// wave = one i x 32 j. C layout: col=lane&31=pair, row d=(r&3)+8*(r>>2)+4*h2
__global__ __launch_bounds__(256, 2) void pair_head_kernel(
    const float* __restrict__ g,      const float* __restrict__ fphg,
    const float* __restrict__ Srow,   const float* __restrict__ ddg,
    const float* __restrict__ consts, const float* __restrict__ eperm,
    const float* __restrict__ cbperm, const unsigned short* __restrict__ aextT,
    float* __restrict__ out)   // out also holds Q on entry
{
    const int tid  = threadIdx.x;
    const int wid  = tid >> 6;
    const int lane = tid & 63;
    const int l5   = lane & 31;
    const int h2   = lane >> 5;
    const int i    = blockIdx.y;
    const int jg   = blockIdx.x * 4 + wid;   // 0..7, each covers 128 j

    // A fragments: fw2^T, lane holds A[d=l5][k=h2*8+e (+16)]
    const bf16x8 af0 = *reinterpret_cast<const bf16x8*>(aextT + l5 * 32 + h2 * 8);
    const bf16x8 af1 = *reinterpret_cast<const bf16x8*>(aextT + l5 * 32 + 16 + h2 * 8);

    // uniform i-side (s_loads) selected into vectors once
    const float* __restrict__ gi = g    + i * DD;
    const float* __restrict__ fh = fphg + i * DD;
    f32x8 gikA, gikB, ckA, ckB;
#pragma unroll
    for (int e = 0; e < 8; ++e) {
        gikA[e] = h2 ? gi[8 + e]  : gi[e];
        gikB[e] = h2 ? gi[24 + e] : gi[16 + e];
        ckA[e]  = h2 ? consts[8 + e]  : consts[e];
        ckB[e]  = h2 ? consts[24 + e] : consts[16 + e];
    }
    f32x16 fihg;
#pragma unroll
    for (int r = 0; r < 16; ++r) {
        const int dr0 = (r & 3) + 8 * (r >> 2);
        fihg[r] = h2 ? fh[dr0 + 4] : fh[dr0];
    }
    const f32x16 cbp = *reinterpret_cast<const f32x16*>(cbperm + h2 * 16);
    const f32x16 ep  = *reinterpret_cast<const f32x16*>(eperm  + h2 * 16);
    const float Si = Srow[i];
    const float di = ddg[i];
    const float E = consts[32], F = consts[33];

#pragma unroll 1
    for (int tt = 0; tt < 4; ++tt) {
        const int j  = jg * 128 + tt * 32 + l5;
        const int jc = j < M_ROWS ? j : M_ROWS - 1;

        // per-lane own-row loads (16B each)
        const float* gj = g + jc * DD + h2 * 8;
        const f32x4 ga = *reinterpret_cast<const f32x4*>(gj);
        const f32x4 gb = *reinterpret_cast<const f32x4*>(gj + 4);
        const f32x4 gc = *reinterpret_cast<const f32x4*>(gj + 16);
        const f32x4 gd = *reinterpret_cast<const f32x4*>(gj + 20);
        const float* fjh = fphg + jc * DD + h2 * 4;
        const f32x4 p0 = *reinterpret_cast<const f32x4*>(fjh);
        const f32x4 p1 = *reinterpret_cast<const f32x4*>(fjh + 8);
        const f32x4 p2 = *reinterpret_cast<const f32x4*>(fjh + 16);
        const f32x4 p3 = *reinterpret_cast<const f32x4*>(fjh + 24);
        const float qd = out[i * M_ROWS + jc];   // Gram value (read precedes write in-wave)
        const float Sj = Srow[jc];
        const float dj = ddg[jc];

        const float s = rsqrtf(fmaf(Si + Sj + 2.f * qd, 1.0f / DD, EPS));

        // h = relu(s*(gi+gj)+c) in the lane's two k-slices
        f32x8 gjA = { ga.x, ga.y, ga.z, ga.w, gb.x, gb.y, gb.z, gb.w };
        f32x8 gjB = { gc.x, gc.y, gc.z, gc.w, gd.x, gd.y, gd.z, gd.w };
        f32x8 tA = (gikA + gjA) * s + ckA;
        f32x8 tB = (gikB + gjB) * s + ckB;
#pragma unroll
        for (int e = 0; e < 8; ++e) { tA[e] = fmaxf(tA[e], 0.f); tB[e] = fmaxf(tB[e], 0.f); }
        const bf16x8 B0 = cvt8(tA);
        const bf16x8 B1 = cvt8(tB);

        f32x16 acc = cbp;
        acc = __builtin_amdgcn_mfma_f32_32x32x16_bf16(af0, B0, acc, 0, 0, 0);
        acc = __builtin_amdgcn_mfma_f32_32x32x16_bf16(af1, B1, acc, 0, 0, 0);

        // + s*(fihg + fjhg) folded per accumulator register
#pragma unroll
        for (int r = 0; r < 16; ++r) {
            const float fv = r < 4 ? p0[r & 3] : r < 8 ? p1[r & 3] : r < 12 ? p2[r & 3] : p3[r & 3];
            acc[r] = fmaf(s, fihg[r] + fv, acc[r]);
        }

        // LN2 folded into dot(ow)
        float sy = 0.f, syy = 0.f, sye = 0.f;
#pragma unroll
        for (int r = 0; r < 16; ++r) {
            const float yv = acc[r];
            sy += yv; syy = fmaf(yv, yv, syy); sye = fmaf(yv, ep[r], sye);
        }
        sy  += __shfl_xor(sy, 32);
        syy += __shfl_xor(syy, 32);
        sye += __shfl_xor(sye, 32);
        const float m2   = sy * (1.0f / DD);
        const float var2 = fmaf(-m2, m2, syy * (1.0f / DD));
        const float s2   = rsqrtf(var2 + EPS);
        const float res  = fmaf(s2, fmaf(-m2, E, sye), F) + di + dj;
        if (h2 == 0 && j < M_ROWS) out[i * M_ROWS + j] = res;
    }
}

extern "C" void kernel_launch(void* const* d_in, const int* in_sizes, int n_in,
                              void* d_out, int out_size, void* d_ws, size_t ws_size,
                              hipStream_t stream) {
    const float* feat = (const float*)d_in[0];
    const float* ddg  = (const float*)d_in[1];
    const float* aw1  = (const float*)d_in[2];
    const float* ab1  = (const float*)d_in[3];
    const float* aw2  = (const float*)d_in[4];
    const float* ab2  = (const float*)d_in[5];
    const float* ag   = (const float*)d_in[6];
    const float* abt  = (const float*)d_in[7];
    const float* hg   = (const float*)d_in[8];
    const float* hbt  = (const float*)d_in[9];
    const float* fw1  = (const float*)d_in[10];
    const float* fb1  = (const float*)d_in[11];
    const float* fw2  = (const float*)d_in[12];
    const float* fb2  = (const float*)d_in[13];
    const float* fg   = (const float*)d_in[14];
    const float* fbt  = (const float*)d_in[15];
    const float* ow   = (const float*)d_in[16];
    const float* ob   = (const float*)d_in[17];
    float* out = (float*)d_out;

    float* ws      = (float*)d_ws;
    float* g       = ws;             // 32000
    float* fphg    = ws + 32000;     // 32000
    float* Srow    = ws + 64000;     // 1000
    float* consts  = ws + 65024;     // 64
    float* eperm   = ws + 65088;     // 32
    float* cbperm  = ws + 65120;     // 32
    unsigned short* aextT = (unsigned short*)(ws + 65152);  // 1024 ushorts
    unsigned short* fpb   = (unsigned short*)(ws + 65664);  // 32000 ushorts

    front_kernel<<<dim3(17), dim3(64), 0, stream>>>(
        feat, aw1, ab1, aw2, ab2, ag, abt, hg,
        fw1, fb1, hbt, fw2, fb2, fg, fbt, ow, ob,
        g, fphg, Srow, consts, eperm, cbperm, aextT, fpb);
    gram_kernel<<<dim3(8, 32), dim3(256), 0, stream>>>(fpb, out);
    pair_head_kernel<<<dim3(2, M_ROWS), dim3(256), 0, stream>>>(
        g, fphg, Srow, ddg, consts, eperm, cbperm, aextT, out);
}